// Round 7
// baseline (124.306 us; speedup 1.0000x reference)
//
#include <hip/hip_runtime.h>
#include <math.h>

#define C_FINE   100
#define C_MID    20
#define C_COARSE 5
#define D        128
#define NROWS    262144
#define NPAIRS   4950   // 100*99/2
#define NBLK4    78     // ceil(4950/64)

#define WPG      768            // kAcc blocks (4 waves each; 51.2KB LDS -> 3 blk/CU, 12 waves/CU)
#define BATCH    16             // rows per batch per block
#define NBATCH   (NROWS/BATCH)  // 16384 (exact)
#define RG       8              // kRed split per class
#define RB       (WPG/RG)       // 96 partials per reduce block
#define PSTR     12928          // partial stride floats (12800 sums + 100 cnt + pad)

// ws layout in floats
#define FP_OFF    0        // fine protos [100][128]
#define DM_OFF    12800    // mid dist table [20][20]
#define DC_OFF    13200    // coarse dist table [5][5]
#define ACC_OFF   13232    // 5 doubles (byte 52928, 8-aligned)
#define DONE_OFF  13244    // int completion counter
#define CNT_OFF   13248    // class counts [100] (float)
#define FSUM_OFF  13360    // fine sums [100][128]
#define PART_OFF  26176    // partials: WPG x PSTR

// ---------------- kAcc: streaming segment-sum, dim-split 4-wave LDS, no hot atomics ----------------
__global__ __launch_bounds__(256) void kAcc(const float* __restrict__ rep,
                                            const int* __restrict__ tgt,
                                            float* __restrict__ ws) {
    __shared__ float acc[C_FINE][D];   // 51.2 KB, block-shared, dim-partitioned by wave
    __shared__ float cnt[C_FINE];
    const int t    = threadIdx.x;
    const int w    = t >> 6;          // wave 0..3 owns dims [32w, 32w+32)
    const int lane = t & 63;
    const int half = lane >> 5;       // 0: even row of pair, 1: odd row
    const int dl   = lane & 31;       // dim within slice
    const int wid  = blockIdx.x;
    const int dimoff = 32 * w + dl;

    for (int e = t; e < C_FINE * D / 4; e += 256)
        ((float4*)acc)[e] = make_float4(0.f, 0.f, 0.f, 0.f);
    if (t < C_FINE) cnt[t] = 0.f;
    if (wid == 0) {   // zero CNT+FSUM region (12912 floats = 3228 float4) for kRed's merge
        for (int e = t; e < 3228; e += 256)
            ((float4*)(ws + CNT_OFF))[e] = make_float4(0.f, 0.f, 0.f, 0.f);
    }
    __syncthreads();

    const int2* tgt2 = (const int2*)tgt;

    float v[8]; int2 cc[8];
    int g = wid;
    {   // prologue load: batch g (16 rows; 8 pairs; 1 dword/lane = 2x128B segments/instr)
        const int base = g * BATCH;
        #pragma unroll
        for (int u = 0; u < 8; ++u) {
            cc[u] = tgt2[base / 2 + u];
            v[u]  = rep[(size_t)(base + 2 * u + half) * D + dimoff];
        }
    }
    for (;;) {
        const int gn = g + WPG;
        if (gn < NBATCH) {
            float vn[8]; int2 ccn[8];
            const int base = gn * BATCH;
            #pragma unroll
            for (int u = 0; u < 8; ++u) {        // issue next batch's loads first
                ccn[u] = tgt2[base / 2 + u];
                vn[u]  = rep[(size_t)(base + 2 * u + half) * D + dimoff];
            }
            #pragma unroll
            for (int u = 0; u < 8; ++u) {        // RMW current batch (LDS, disjoint dims/wave)
                const int c = half ? cc[u].y : cc[u].x;
                acc[c][dimoff] += v[u];
                if (w == 0 && dl == 0)
                    atomicAdd(&cnt[c], 1.f);
            }
            #pragma unroll
            for (int u = 0; u < 8; ++u) { v[u] = vn[u]; cc[u] = ccn[u]; }
            g = gn;
        } else {
            #pragma unroll
            for (int u = 0; u < 8; ++u) {
                const int c = half ? cc[u].y : cc[u].x;
                acc[c][dimoff] += v[u];
                if (w == 0 && dl == 0)
                    atomicAdd(&cnt[c], 1.f);
            }
            break;
        }
    }
    __syncthreads();

    float* part = ws + PART_OFF + (size_t)wid * PSTR;
    for (int e = t; e < C_FINE * D / 4; e += 256)
        ((float4*)part)[e] = ((const float4*)acc)[e];
    if (t < C_FINE) part[12800 + t] = cnt[t];
}

// ---------------- kRed: merge 768 partials -> FSUM + CNT (atomic, L2/L3-hot) ----------------
__global__ __launch_bounds__(128) void kRed(float* __restrict__ ws) {
    const int c = blockIdx.x >> 3, g = blockIdx.x & 7;
    const int t = threadIdx.x;
    const float* p = ws + PART_OFF + (size_t)(g * RB) * PSTR + c * D + t;
    float s = 0.f;
    #pragma unroll 8
    for (int b = 0; b < RB; ++b) s += p[(size_t)b * PSTR];
    atomicAdd(ws + FSUM_OFF + c * D + t, s);

    float cl = (t < RB) ? ws[PART_OFF + (size_t)(g * RB + t) * PSTR + 12800 + c] : 0.f;
    for (int off = 32; off > 0; off >>= 1) cl += __shfl_down(cl, off);
    __shared__ float r2[2];
    if ((t & 63) == 0) r2[t >> 6] = cl;
    __syncthreads();
    if (t == 0) atomicAdd(ws + CNT_OFF + c, r2[0] + r2[1]);
}

// ---------------- k3: normalize + hierarchy + distance tables (all in LDS) ----------------
__global__ __launch_bounds__(256) void k3_hier(const int* __restrict__ f2m,
                                               const int* __restrict__ f2c,
                                               float* __restrict__ ws) {
    __shared__ float fineP[C_FINE][D];        // 51.2 KB
    __shared__ float midP[C_MID][D + 1];
    __shared__ float coarP[C_COARSE][D + 1];
    __shared__ int   sf2m[C_FINE], sf2c[C_FINE], m2c[C_MID];
    __shared__ float midCnt[C_MID], coarCnt[C_COARSE];
    __shared__ float sTot[C_FINE];
    const int t = threadIdx.x;

    if (t < C_FINE) {
        sf2m[t] = f2m[t]; sf2c[t] = f2c[t];
        sTot[t] = ws[CNT_OFF + t];
    }
    for (int e = t; e < C_MID * (D + 1); e += 256) ((float*)midP)[e] = 0.f;
    for (int e = t; e < C_COARSE * (D + 1); e += 256) ((float*)coarP)[e] = 0.f;
    __syncthreads();

    // normalize fine sums -> fineP (LDS + global for k45)
    for (int e = t; e < C_FINE * D; e += 256) {
        int c = e >> 7, d = e & 127;
        float v = ws[FSUM_OFF + e] / fmaxf(sTot[c], 1.f);
        fineP[c][d] = v;
        ws[FP_OFF + e] = v;
    }
    if (t < C_MID) {
        int cntv = 0, mx = -2147483647;
        for (int f = 0; f < C_FINE; ++f)
            if (sf2m[f] == t) { ++cntv; mx = max(mx, sf2c[f]); }
        midCnt[t] = (float)max(cntv, 1);
        m2c[t] = mx;
    }
    __syncthreads();

    if (t < D) {
        const int d = t;
        for (int f = 0; f < C_FINE; ++f)
            midP[sf2m[f]][d] += fineP[f][d];
        for (int m = 0; m < C_MID; ++m)
            midP[m][d] /= midCnt[m];
    }
    if (t >= 128 && t < 128 + C_COARSE) {
        int cc = t - 128, cntv = 0;
        for (int m = 0; m < C_MID; ++m) if (m2c[m] == cc) ++cntv;
        coarCnt[cc] = (float)max(cntv, 1);
    }
    __syncthreads();

    if (t < D) {
        const int d = t;
        for (int m = 0; m < C_MID; ++m)
            coarP[m2c[m]][d] += midP[m][d];
        for (int cc = 0; cc < C_COARSE; ++cc)
            coarP[cc][d] /= coarCnt[cc];
    }
    __syncthreads();

    for (int e = t; e < C_MID * C_MID; e += 256) {
        int m1 = e / C_MID, m2 = e % C_MID;
        float ss = 0.f;
        #pragma unroll 8
        for (int d = 0; d < D; ++d) {
            float df = midP[m1][d] - midP[m2][d];
            ss += df * df;
        }
        ws[DM_OFF + e] = sqrtf(ss + 1e-12f);
    }
    for (int e = t; e < C_COARSE * C_COARSE; e += 256) {
        int c1 = e / C_COARSE, c2 = e % C_COARSE;
        float ss = 0.f;
        #pragma unroll 8
        for (int d = 0; d < D; ++d) {
            float df = coarP[c1][d] - coarP[c2][d];
            ss += df * df;
        }
        ws[DC_OFF + e] = sqrtf(ss + 1e-12f);
    }
    if (t < 5) ((double*)(ws + ACC_OFF))[t] = 0.0;   // zero moment accumulators
    if (t == 5) ((int*)ws + DONE_OFF)[0] = 0;        // zero completion counter
}

// ---------------- k45: all fine pairs -> moments, last block finalizes ----------------
__global__ __launch_bounds__(64) void k45_pairs(float* __restrict__ ws,
                                                const int* __restrict__ f2m,
                                                const int* __restrict__ f2c,
                                                float* __restrict__ out) {
    const int p = blockIdx.x * 64 + threadIdx.x;
    double st = 0, sp = 0, stp = 0, stt = 0, spp = 0;
    if (p < NPAIRS) {
        int i = 0, rem = p;
        while (rem >= C_FINE - 1 - i) { rem -= C_FINE - 1 - i; ++i; }
        int j = i + 1 + rem;

        const float4* Fi = (const float4*)(ws + FP_OFF + i * D);
        const float4* Fj = (const float4*)(ws + FP_OFF + j * D);
        float ss = 0.f;
        #pragma unroll
        for (int k = 0; k < D / 4; ++k) {
            float4 a = Fi[k], b = Fj[k];
            float dx = a.x - b.x, dy = a.y - b.y, dz = a.z - b.z, dw = a.w - b.w;
            ss += dx * dx + dy * dy + dz * dz + dw * dw;
        }
        float proto = sqrtf(ss + 1e-12f);
        float tree  = ws[DC_OFF + f2c[i] * C_COARSE + f2c[j]]
                    + ws[DM_OFF + f2m[i] * C_MID + f2m[j]];
        st = tree; sp = proto;
        stp = (double)tree * (double)proto;
        stt = (double)tree * (double)tree;
        spp = (double)proto * (double)proto;
    }
    for (int off = 32; off > 0; off >>= 1) {
        st  += __shfl_down(st, off);
        sp  += __shfl_down(sp, off);
        stp += __shfl_down(stp, off);
        stt += __shfl_down(stt, off);
        spp += __shfl_down(spp, off);
    }
    if (threadIdx.x == 0) {
        double* acc = (double*)(ws + ACC_OFF);
        atomicAdd(&acc[0], st);
        atomicAdd(&acc[1], sp);
        atomicAdd(&acc[2], stp);
        atomicAdd(&acc[3], stt);
        atomicAdd(&acc[4], spp);
        __threadfence();
        int* done = (int*)ws + DONE_OFF;
        int ticket = atomicAdd(done, 1);
        if (ticket == NBLK4 - 1) {
            double fst  = atomicAdd(&acc[0], 0.0);
            double fsp  = atomicAdd(&acc[1], 0.0);
            double fstp = atomicAdd(&acc[2], 0.0);
            double fstt = atomicAdd(&acc[3], 0.0);
            double fspp = atomicAdd(&acc[4], 0.0);
            const double n = (double)NPAIRS;
            double num = fstp - fst * fsp / n;
            double dtt = fstt - fst * fst / n;
            double dpp = fspp - fsp * fsp / n;
            double corr = num / sqrt(dtt * dpp + 1e-12);
            out[0] = (float)(1.0 - corr);
        }
    }
}

extern "C" void kernel_launch(void* const* d_in, const int* in_sizes, int n_in,
                              void* d_out, int out_size, void* d_ws, size_t ws_size,
                              hipStream_t stream) {
    const float* rep = (const float*)d_in[0];
    const int*   tgt = (const int*)d_in[1];
    const int*   f2m = (const int*)d_in[2];
    const int*   f2c = (const int*)d_in[3];
    float* ws  = (float*)d_ws;
    float* out = (float*)d_out;

    hipLaunchKernelGGL(kAcc,      dim3(WPG),         dim3(256), 0, stream, rep, tgt, ws);
    hipLaunchKernelGGL(kRed,      dim3(C_FINE * RG), dim3(128), 0, stream, ws);
    hipLaunchKernelGGL(k3_hier,   dim3(1),           dim3(256), 0, stream, f2m, f2c, ws);
    hipLaunchKernelGGL(k45_pairs, dim3(NBLK4),       dim3(64),  0, stream,
                       ws, f2m, f2c, out);
}

// Round 8
// 81.987 us; speedup vs baseline: 1.5162x; 1.5162x over previous
//
#include <hip/hip_runtime.h>
#include <math.h>

#define C_FINE   100
#define C_MID    20
#define C_COARSE 5
#define D        128
#define NROWS    262144
#define NPAIRS   4950   // 100*99/2
#define NBLK4    78     // ceil(4950/64)

#define NB       512              // kMF blocks
#define ROWS_PB  (NROWS/NB)       // 512 rows per block
#define NSTEP    (ROWS_PB/32)     // 16 K-steps of 32 rows
#define MT       7                // 112 padded classes / 16
#define PSTR2    (113*128)        // per-block partial: [112][128] sums + [128] cnt row

// ws layout in floats
#define FP_OFF    0        // fine protos [100][128]
#define DM_OFF    12800    // mid dist table [20][20]
#define DC_OFF    13200    // coarse dist table [5][5]
#define ACC_OFF   13232    // 5 doubles (byte 52928, 8-aligned)
#define DONE_OFF  13244    // int completion counter
#define CNT_OFF   13248    // class counts [100] (float), padded to 128
#define FSUM_OFF  13376    // fine sums [100][128]
#define PART_OFF  26176    // partials: NB x PSTR2  (~29.7 MB)

typedef __attribute__((ext_vector_type(8))) short bf16x8;   // 8 bf16 (4 VGPRs)
typedef __attribute__((ext_vector_type(4))) float f32x4;    // MFMA C/D

static __device__ __forceinline__ unsigned short f2bf(float f) {
    unsigned int x = __float_as_uint(f);
    x += 0x7FFF + ((x >> 16) & 1);      // round-to-nearest-even
    return (unsigned short)(x >> 16);
}

// ---------------- kMF: segment-sum as one-hot MFMA GEMM ----------------
// C[class 112][dim 128] += onehot(tgt)[112][k32] * rep[k32][128] per K-step.
// A-frag lane l: m=l&15 (+16*mt), k=8*(l>>4)+j  -> (tgt[row]==class)?1:0
// B-frag lane l: n=l&15 (+16*nt+32*w), k=8*(l>>4)+j -> bf16(rep[row][col])
// C/D  lane l: col=l&15, row=4*(l>>4)+i (m89-verified)
__global__ __launch_bounds__(256) void kMF(const float* __restrict__ rep,
                                           const int* __restrict__ tgt,
                                           float* __restrict__ ws) {
    __shared__ int hist[128];
    const int t  = threadIdx.x;
    const int w  = t >> 6;          // wave 0..3 owns cols [32w, 32w+32)
    const int l  = t & 63;
    const int lg = l >> 4;          // k-group 0..3
    const int ll = l & 15;
    const int blk   = blockIdx.x;
    const int rbase = blk * ROWS_PB;

    if (t < 128) hist[t] = 0;
    __syncthreads();
    atomicAdd(&hist[tgt[rbase + t]], 1);
    atomicAdd(&hist[tgt[rbase + t + 256]], 1);

    const int colbase = 32 * w + ll;

    f32x4 acc[MT][2];
    #pragma unroll
    for (int m = 0; m < MT; ++m)
        #pragma unroll
        for (int n = 0; n < 2; ++n)
            #pragma unroll
            for (int i = 0; i < 4; ++i) acc[m][n][i] = 0.f;

    float vA[16], vB[16];
    int   tA[8],  tB[8];

#define LOADSTEP(V, T, s) do {                                                  \
    const float* p_ = rep + ((size_t)(rbase + (s) * 32 + 8 * lg) * D + colbase);\
    _Pragma("unroll")                                                           \
    for (int j_ = 0; j_ < 8; ++j_) {                                            \
        V[j_]     = p_[j_ * D];                                                 \
        V[8 + j_] = p_[j_ * D + 16];                                            \
    }                                                                           \
    const int* q_ = tgt + (rbase + (s) * 32 + 8 * lg);                          \
    _Pragma("unroll")                                                           \
    for (int j_ = 0; j_ < 8; ++j_) T[j_] = q_[j_];                              \
} while (0)

#define COMPSTEP(V, T) do {                                                     \
    bf16x8 b0_, b1_;                                                            \
    _Pragma("unroll")                                                           \
    for (int j_ = 0; j_ < 8; ++j_) {                                            \
        b0_[j_] = (short)f2bf(V[j_]);                                           \
        b1_[j_] = (short)f2bf(V[8 + j_]);                                       \
    }                                                                           \
    _Pragma("unroll")                                                           \
    for (int m_ = 0; m_ < MT; ++m_) {                                           \
        const int cb_ = 16 * m_ + ll;                                           \
        bf16x8 a_;                                                              \
        _Pragma("unroll")                                                       \
        for (int j_ = 0; j_ < 8; ++j_)                                          \
            a_[j_] = (T[j_] == cb_) ? (short)0x3F80 : (short)0;                 \
        acc[m_][0] = __builtin_amdgcn_mfma_f32_16x16x32_bf16(a_, b0_, acc[m_][0], 0, 0, 0); \
        acc[m_][1] = __builtin_amdgcn_mfma_f32_16x16x32_bf16(a_, b1_, acc[m_][1], 0, 0, 0); \
    }                                                                           \
} while (0)

    LOADSTEP(vA, tA, 0);
    #pragma unroll 1
    for (int s = 0; s < NSTEP; s += 2) {
        LOADSTEP(vB, tB, s + 1);
        COMPSTEP(vA, tA);
        if (s + 2 < NSTEP) LOADSTEP(vA, tA, s + 2);
        COMPSTEP(vB, tB);
    }
#undef LOADSTEP
#undef COMPSTEP

    float* part = ws + PART_OFF + (size_t)blk * PSTR2;
    #pragma unroll
    for (int m = 0; m < MT; ++m)
        #pragma unroll
        for (int n = 0; n < 2; ++n)
            #pragma unroll
            for (int i = 0; i < 4; ++i)
                part[(16 * m + 4 * lg + i) * D + 32 * w + 16 * n + ll] = acc[m][n][i];
    __syncthreads();
    if (t < 128) part[112 * D + t] = (t < C_FINE) ? (float)hist[t] : 0.f;
}

// ---------------- kRed: merge NB partials -> FSUM + CNT (no atomics) ----------------
__global__ __launch_bounds__(512) void kRed(float* __restrict__ ws) {
    const int c = blockIdx.x;            // class 0..99
    const int t = threadIdx.x;
    const int g = t >> 7, d = t & 127;
    float s = 0.f;
    #pragma unroll 8
    for (int b = g; b < NB; b += 4)
        s += ws[PART_OFF + (size_t)b * PSTR2 + c * D + d];
    __shared__ float red[4][128];
    red[g][d] = s;

    float cv = ws[PART_OFF + (size_t)t * PSTR2 + 112 * D + c];   // t < NB == 512
    #pragma unroll
    for (int off = 32; off > 0; off >>= 1) cv += __shfl_down(cv, off);
    __shared__ float cw[8];
    if ((t & 63) == 0) cw[t >> 6] = cv;
    __syncthreads();
    if (g == 0) ws[FSUM_OFF + c * D + d] = red[0][d] + red[1][d] + red[2][d] + red[3][d];
    if (t == 0) {
        float tot = 0.f;
        #pragma unroll
        for (int q = 0; q < 8; ++q) tot += cw[q];
        ws[CNT_OFF + c] = tot;
    }
}

// ---------------- k3: normalize + hierarchy + distance tables (all in LDS) ----------------
__global__ __launch_bounds__(256) void k3_hier(const int* __restrict__ f2m,
                                               const int* __restrict__ f2c,
                                               float* __restrict__ ws) {
    __shared__ float fineP[C_FINE][D];        // 51.2 KB
    __shared__ float midP[C_MID][D + 1];
    __shared__ float coarP[C_COARSE][D + 1];
    __shared__ int   sf2m[C_FINE], sf2c[C_FINE], m2c[C_MID];
    __shared__ float midCnt[C_MID], coarCnt[C_COARSE];
    __shared__ float sTot[C_FINE];
    const int t = threadIdx.x;

    if (t < C_FINE) {
        sf2m[t] = f2m[t]; sf2c[t] = f2c[t];
        sTot[t] = ws[CNT_OFF + t];
    }
    for (int e = t; e < C_MID * (D + 1); e += 256) ((float*)midP)[e] = 0.f;
    for (int e = t; e < C_COARSE * (D + 1); e += 256) ((float*)coarP)[e] = 0.f;
    __syncthreads();

    for (int e = t; e < C_FINE * D; e += 256) {
        int c = e >> 7, d = e & 127;
        float v = ws[FSUM_OFF + e] / fmaxf(sTot[c], 1.f);
        fineP[c][d] = v;
        ws[FP_OFF + e] = v;
    }
    if (t < C_MID) {
        int cntv = 0, mx = -2147483647;
        for (int f = 0; f < C_FINE; ++f)
            if (sf2m[f] == t) { ++cntv; mx = max(mx, sf2c[f]); }
        midCnt[t] = (float)max(cntv, 1);
        m2c[t] = mx;
    }
    __syncthreads();

    if (t < D) {
        const int d = t;
        for (int f = 0; f < C_FINE; ++f)
            midP[sf2m[f]][d] += fineP[f][d];
        for (int m = 0; m < C_MID; ++m)
            midP[m][d] /= midCnt[m];
    }
    if (t >= 128 && t < 128 + C_COARSE) {
        int cc = t - 128, cntv = 0;
        for (int m = 0; m < C_MID; ++m) if (m2c[m] == cc) ++cntv;
        coarCnt[cc] = (float)max(cntv, 1);
    }
    __syncthreads();

    if (t < D) {
        const int d = t;
        for (int m = 0; m < C_MID; ++m)
            coarP[m2c[m]][d] += midP[m][d];
        for (int cc = 0; cc < C_COARSE; ++cc)
            coarP[cc][d] /= coarCnt[cc];
    }
    __syncthreads();

    for (int e = t; e < C_MID * C_MID; e += 256) {
        int m1 = e / C_MID, m2 = e % C_MID;
        float ss = 0.f;
        #pragma unroll 8
        for (int d = 0; d < D; ++d) {
            float df = midP[m1][d] - midP[m2][d];
            ss += df * df;
        }
        ws[DM_OFF + e] = sqrtf(ss + 1e-12f);
    }
    for (int e = t; e < C_COARSE * C_COARSE; e += 256) {
        int c1 = e / C_COARSE, c2 = e % C_COARSE;
        float ss = 0.f;
        #pragma unroll 8
        for (int d = 0; d < D; ++d) {
            float df = coarP[c1][d] - coarP[c2][d];
            ss += df * df;
        }
        ws[DC_OFF + e] = sqrtf(ss + 1e-12f);
    }
    if (t < 5) ((double*)(ws + ACC_OFF))[t] = 0.0;   // zero moment accumulators
    if (t == 5) ((int*)ws + DONE_OFF)[0] = 0;        // zero completion counter
}

// ---------------- k45: all fine pairs -> moments, last block finalizes ----------------
__global__ __launch_bounds__(64) void k45_pairs(float* __restrict__ ws,
                                                const int* __restrict__ f2m,
                                                const int* __restrict__ f2c,
                                                float* __restrict__ out) {
    const int p = blockIdx.x * 64 + threadIdx.x;
    double st = 0, sp = 0, stp = 0, stt = 0, spp = 0;
    if (p < NPAIRS) {
        int i = 0, rem = p;
        while (rem >= C_FINE - 1 - i) { rem -= C_FINE - 1 - i; ++i; }
        int j = i + 1 + rem;

        const float4* Fi = (const float4*)(ws + FP_OFF + i * D);
        const float4* Fj = (const float4*)(ws + FP_OFF + j * D);
        float ss = 0.f;
        #pragma unroll
        for (int k = 0; k < D / 4; ++k) {
            float4 a = Fi[k], b = Fj[k];
            float dx = a.x - b.x, dy = a.y - b.y, dz = a.z - b.z, dw = a.w - b.w;
            ss += dx * dx + dy * dy + dz * dz + dw * dw;
        }
        float proto = sqrtf(ss + 1e-12f);
        float tree  = ws[DC_OFF + f2c[i] * C_COARSE + f2c[j]]
                    + ws[DM_OFF + f2m[i] * C_MID + f2m[j]];
        st = tree; sp = proto;
        stp = (double)tree * (double)proto;
        stt = (double)tree * (double)tree;
        spp = (double)proto * (double)proto;
    }
    for (int off = 32; off > 0; off >>= 1) {
        st  += __shfl_down(st, off);
        sp  += __shfl_down(sp, off);
        stp += __shfl_down(stp, off);
        stt += __shfl_down(stt, off);
        spp += __shfl_down(spp, off);
    }
    if (threadIdx.x == 0) {
        double* acc = (double*)(ws + ACC_OFF);
        atomicAdd(&acc[0], st);
        atomicAdd(&acc[1], sp);
        atomicAdd(&acc[2], stp);
        atomicAdd(&acc[3], stt);
        atomicAdd(&acc[4], spp);
        __threadfence();
        int* done = (int*)ws + DONE_OFF;
        int ticket = atomicAdd(done, 1);
        if (ticket == NBLK4 - 1) {
            double fst  = atomicAdd(&acc[0], 0.0);
            double fsp  = atomicAdd(&acc[1], 0.0);
            double fstp = atomicAdd(&acc[2], 0.0);
            double fstt = atomicAdd(&acc[3], 0.0);
            double fspp = atomicAdd(&acc[4], 0.0);
            const double n = (double)NPAIRS;
            double num = fstp - fst * fsp / n;
            double dtt = fstt - fst * fst / n;
            double dpp = fspp - fsp * fsp / n;
            double corr = num / sqrt(dtt * dpp + 1e-12);
            out[0] = (float)(1.0 - corr);
        }
    }
}

extern "C" void kernel_launch(void* const* d_in, const int* in_sizes, int n_in,
                              void* d_out, int out_size, void* d_ws, size_t ws_size,
                              hipStream_t stream) {
    const float* rep = (const float*)d_in[0];
    const int*   tgt = (const int*)d_in[1];
    const int*   f2m = (const int*)d_in[2];
    const int*   f2c = (const int*)d_in[3];
    float* ws  = (float*)d_ws;
    float* out = (float*)d_out;

    hipLaunchKernelGGL(kMF,       dim3(NB),     dim3(256), 0, stream, rep, tgt, ws);
    hipLaunchKernelGGL(kRed,      dim3(C_FINE), dim3(512), 0, stream, ws);
    hipLaunchKernelGGL(k3_hier,   dim3(1),      dim3(256), 0, stream, f2m, f2c, ws);
    hipLaunchKernelGGL(k45_pairs, dim3(NBLK4),  dim3(64),  0, stream,
                       ws, f2m, f2c, out);
}